// Round 3
// baseline (1048.785 us; speedup 1.0000x reference)
//
#include <hip/hip_runtime.h>
#include <hip/hip_bf16.h>

#define EPSF 1e-5f

static constexpr int NGRAPH = 64;
static constexpr int HB = 16384;  // deg-histogram bins (64 KB LDS as u32)
static constexpr int CHK = 32;    // deg-histogram edge chunks
static constexpr int HBA = 4096;  // acc bins: 4 x f32 x 4096 = 64 KB LDS
static constexpr int CHKA = 9;    // acc edge chunks (225 blocks with RA=25)

__device__ __forceinline__ void gAtomicAdd(float* p, float v) {
  unsafeAtomicAdd(p, v);  // native global_atomic_add_f32 on gfx950
}

// ---------- BN0 stats over x [N,4]: sum[4], sumsq[4] -> stats[8] ----------
__global__ void k_bnstats(const float4* __restrict__ x, int N,
                          float* __restrict__ stats) {
  float s[4] = {0, 0, 0, 0}, q[4] = {0, 0, 0, 0};
  for (int i = blockIdx.x * blockDim.x + threadIdx.x; i < N;
       i += gridDim.x * blockDim.x) {
    float4 v = x[i];
    s[0] += v.x; q[0] += v.x * v.x;
    s[1] += v.y; q[1] += v.y * v.y;
    s[2] += v.z; q[2] += v.z * v.z;
    s[3] += v.w; q[3] += v.w * v.w;
  }
#pragma unroll
  for (int o = 32; o > 0; o >>= 1) {
#pragma unroll
    for (int k = 0; k < 4; k++) {
      s[k] += __shfl_down(s[k], o);
      q[k] += __shfl_down(q[k], o);
    }
  }
  if ((threadIdx.x & 63) == 0) {
#pragma unroll
    for (int k = 0; k < 4; k++) {
      gAtomicAdd(&stats[k], s[k]);
      gAtomicAdd(&stats[4 + k], q[k]);
    }
  }
}

// ---------- degree histogram: node-range partitioned, no global atomics ----
__global__ void k_hist(const int* __restrict__ ei, int E, int R, int chunk,
                       unsigned* __restrict__ part) {
  __shared__ unsigned h[HB];
  for (int t = threadIdx.x; t < HB; t += blockDim.x) h[t] = 0;
  __syncthreads();
  int r = blockIdx.x % R, c = blockIdx.x / R;
  int lo = c * chunk;
  int hi = min(E, lo + chunk);
  int base = r * HB;
  for (int e = lo + threadIdx.x; e < hi; e += blockDim.x) {
    unsigned rel = (unsigned)(ei[E + e] - base);
    if (rel < (unsigned)HB) atomicAdd(&h[rel], 1u);
  }
  __syncthreads();
  unsigned* out = part + (size_t)blockIdx.x * HB;
  for (int t = threadIdx.x; t < HB; t += blockDim.x) out[t] = h[t];
}

__global__ void k_degreduce(const unsigned* __restrict__ part, int N, int R,
                            unsigned* __restrict__ degcnt) {
  int v = blockIdx.x * blockDim.x + threadIdx.x;
  if (v >= N) return;
  int r = v / HB, off = v - r * HB;
  unsigned s = 0;
#pragma unroll 4
  for (int c = 0; c < CHK; c++) s += part[(size_t)(c * R + r) * HB + off];
  degcnt[v] = s;
}

// fallback if ws too small for partials
__global__ void k_degatomic(const int* __restrict__ ei, int E,
                            unsigned* __restrict__ degcnt) {
  for (int e = blockIdx.x * blockDim.x + threadIdx.x; e < E;
       e += gridDim.x * blockDim.x)
    atomicAdd(&degcnt[ei[E + e]], 1u);
}

__device__ __forceinline__ void bn0_coefs(const float* __restrict__ stats,
                                          const float* __restrict__ g,
                                          const float* __restrict__ b,
                                          float Ninv, float* sc, float* sh) {
#pragma unroll
  for (int k = 0; k < 4; k++) {
    float mu = stats[k] * Ninv;
    float var = stats[4 + k] * Ninv - mu * mu;
    var = var < 0.f ? 0.f : var;
    float s = g[k] / sqrtf(var + EPSF);
    sc[k] = s;
    sh[k] = b[k] - mu * s;
  }
}

// ---------- per-node prep: xz = dinv * xbn (f32, exact) --------------------
__global__ void k_prep(const float4* __restrict__ x,
                       const unsigned* __restrict__ degcnt, int N,
                       const float* __restrict__ stats,
                       const float* __restrict__ bn0g,
                       const float* __restrict__ bn0b, float Ninv,
                       float4* __restrict__ xz) {
  int i = blockIdx.x * blockDim.x + threadIdx.x;
  if (i >= N) return;
  float sc[4], sh[4];
  bn0_coefs(stats, bn0g, bn0b, Ninv, sc, sh);
  float dv = rsqrtf((float)degcnt[i] + 1.0f);
  float4 xv = x[i];
  float4 z;
  z.x = dv * (xv.x * sc[0] + sh[0]);
  z.y = dv * (xv.y * sc[1] + sh[1]);
  z.z = dv * (xv.z * sc[2] + sh[2]);
  z.w = dv * (xv.w * sc[3] + sh[3]);
  xz[i] = z;
}

// ---------- edge accumulate: LDS range-partitioned, no global atomics ------
// part[block] = 4096 x float4 partial sums of xz[src] binned by dst range.
__global__ void k_accA(const int* __restrict__ ei, int E, int RA, int chunk,
                       const float4* __restrict__ xz,
                       float4* __restrict__ part) {
  __shared__ float h[4 * HBA];  // channel-planar, 64 KB
  for (int t = threadIdx.x; t < 4 * HBA; t += blockDim.x) h[t] = 0.f;
  __syncthreads();
  int r = blockIdx.x % RA, c = blockIdx.x / RA;
  int base = r * HBA;
  int lo = c * chunk;
  int hi = min(E, lo + chunk);
  for (int e = lo + threadIdx.x; e < hi; e += blockDim.x) {
    unsigned rel = (unsigned)(ei[E + e] - base);
    if (rel < (unsigned)HBA) {
      int s = ei[e];
      float4 v = xz[s];
      atomicAdd(&h[rel], v.x);
      atomicAdd(&h[HBA + rel], v.y);
      atomicAdd(&h[2 * HBA + rel], v.z);
      atomicAdd(&h[3 * HBA + rel], v.w);
    }
  }
  __syncthreads();
  float4* out = part + (size_t)blockIdx.x * HBA;
  for (int t = threadIdx.x; t < HBA; t += blockDim.x)
    out[t] = make_float4(h[t], h[HBA + t], h[2 * HBA + t], h[3 * HBA + t]);
}

// fallback: direct f32 global atomics
__global__ void k_edgeA_f32(const int* __restrict__ ei, int E,
                            const float4* __restrict__ xz,
                            float4* __restrict__ acc) {
  for (int e = blockIdx.x * blockDim.x + threadIdx.x; e < E;
       e += gridDim.x * blockDim.x) {
    int s = ei[e];
    int d = ei[E + e];
    float4 v = xz[s];
    float* a = (float*)(acc + d);
    gAtomicAdd(a + 0, v.x);
    gAtomicAdd(a + 1, v.y);
    gAtomicAdd(a + 2, v.z);
    gAtomicAdd(a + 3, v.w);
  }
}

// ---------- node pass: reduce partials -> p2, nodeS; node terms of U/S/cnt -
// nodeS[2v] = p2 (float4); nodeS[2v+1] = {dinv, graph, 0, 0}
__global__ void k_nodeB(const float4* __restrict__ part,
                        const float4* __restrict__ accf4, int fits,
                        const unsigned* __restrict__ degcnt,
                        const float4* __restrict__ xz,
                        const int* __restrict__ batch, int N, int RA,
                        float4* __restrict__ nodeS, float* __restrict__ U,
                        float* __restrict__ S, float* __restrict__ cnt) {
  __shared__ float lac[NGRAPH * 7];
  for (int t = threadIdx.x; t < NGRAPH * 7; t += blockDim.x) lac[t] = 0.f;
  __syncthreads();
  for (int v = blockIdx.x * blockDim.x + threadIdx.x; v < N;
       v += gridDim.x * blockDim.x) {
    float4 a;
    if (fits) {
      int r = v >> 12, off = v & (HBA - 1);
      a = make_float4(0.f, 0.f, 0.f, 0.f);
      size_t b0 = (size_t)r * HBA + off;
#pragma unroll
      for (int c = 0; c < CHKA; c++) {
        float4 p = part[b0 + (size_t)c * RA * HBA];
        a.x += p.x; a.y += p.y; a.z += p.z; a.w += p.w;
      }
    } else {
      a = accf4[v];
    }
    float dv = rsqrtf((float)degcnt[v] + 1.0f);
    float idg = dv * dv;
    float4 z = xz[v];
    float4 p2;  // p2 = dinv * pre1 = invdeg * (accsum + z)
    p2.x = idg * (a.x + z.x);
    p2.y = idg * (a.y + z.y);
    p2.z = idg * (a.z + z.z);
    p2.w = idg * (a.w + z.w);
    int g = batch[v];
    nodeS[2 * (size_t)v] = p2;
    nodeS[2 * (size_t)v + 1] = make_float4(dv, (float)g, 0.f, 0.f);
    int g7 = g * 7;
    atomicAdd(&lac[g7 + 0], dv * p2.x);
    atomicAdd(&lac[g7 + 1], dv * p2.y);
    atomicAdd(&lac[g7 + 2], dv * p2.z);
    atomicAdd(&lac[g7 + 3], dv * p2.w);
    atomicAdd(&lac[g7 + 4], idg);
    atomicAdd(&lac[g7 + 5], 1.0f);
  }
  __syncthreads();
  if (threadIdx.x < NGRAPH) {
    int t = threadIdx.x;
    gAtomicAdd(&U[t * 4 + 0], lac[t * 7 + 0]);
    gAtomicAdd(&U[t * 4 + 1], lac[t * 7 + 1]);
    gAtomicAdd(&U[t * 4 + 2], lac[t * 7 + 2]);
    gAtomicAdd(&U[t * 4 + 3], lac[t * 7 + 3]);
    gAtomicAdd(&S[t], lac[t * 7 + 4]);
    gAtomicAdd(&cnt[t], lac[t * 7 + 5]);
  }
}

// ---------- edge pass B: per-graph U += dinv[d]*p2[src], S += w ------------
__global__ void k_edgeB(const int* __restrict__ ei, int E,
                        const float4* __restrict__ nodeS,
                        float* __restrict__ U, float* __restrict__ S) {
  __shared__ float lac[4 * NGRAPH * 5];  // per-wave replicas
  for (int t = threadIdx.x; t < 4 * NGRAPH * 5; t += blockDim.x) lac[t] = 0.f;
  __syncthreads();
  float* wl = lac + (threadIdx.x >> 6) * (NGRAPH * 5);
  for (int e = blockIdx.x * blockDim.x + threadIdx.x; e < E;
       e += gridDim.x * blockDim.x) {
    int s = ei[e];
    int d = ei[E + e];
    float4 dd = nodeS[2 * (size_t)d + 1];  // {dinv_d, graph_d}
    float4 p = nodeS[2 * (size_t)s];       // p2[s]
    float4 sd = nodeS[2 * (size_t)s + 1];  // {dinv_s, ...} same line as p
    float dvd = dd.x;
    int g5 = (int)dd.y * 5;
    atomicAdd(&wl[g5 + 0], dvd * p.x);
    atomicAdd(&wl[g5 + 1], dvd * p.y);
    atomicAdd(&wl[g5 + 2], dvd * p.z);
    atomicAdd(&wl[g5 + 3], dvd * p.w);
    atomicAdd(&wl[g5 + 4], dvd * sd.x);
  }
  __syncthreads();
  if (threadIdx.x < NGRAPH) {
    int t = threadIdx.x;
    float u0 = 0, u1 = 0, u2 = 0, u3 = 0, ws = 0;
#pragma unroll
    for (int w = 0; w < 4; w++) {
      const float* b = lac + w * (NGRAPH * 5) + t * 5;
      u0 += b[0]; u1 += b[1]; u2 += b[2]; u3 += b[3]; ws += b[4];
    }
    gAtomicAdd(&U[t * 4 + 0], u0);
    gAtomicAdd(&U[t * 4 + 1], u1);
    gAtomicAdd(&U[t * 4 + 2], u2);
    gAtomicAdd(&U[t * 4 + 3], u3);
    gAtomicAdd(&S[t], ws);
  }
}

// ---------- epilogue: g_raw = U@(W0W1)+S*(b0W1)+cnt*b1 -> BN -> MLP --------
__global__ void k_final(const float* __restrict__ U, const float* __restrict__ S,
                        const float* __restrict__ cnt,
                        const float* __restrict__ W0, const float* __restrict__ b0,
                        const float* __restrict__ W1, const float* __restrict__ b1,
                        const float* __restrict__ bn1g,
                        const float* __restrict__ bn1b,
                        const float* __restrict__ l0W, const float* __restrict__ l0b,
                        const float* __restrict__ l1W, const float* __restrict__ l1b,
                        const float* __restrict__ oW, const float* __restrict__ ob,
                        float* __restrict__ out) {
  __shared__ float sW01[4 * 64];
  __shared__ float sb01[64];
  __shared__ float sA[64 * 64];
  __shared__ float sB[64 * 64];
  __shared__ float sSc[64], sSh[64];
  int t = threadIdx.x;
  {
    int k = t >> 6, f = t & 63;
    float a = 0.f;
    for (int j = 0; j < 64; j++) a += W0[k * 64 + j] * W1[j * 64 + f];
    sW01[k * 64 + f] = a;
  }
  if (t < 64) {
    float a = 0.f;
    for (int j = 0; j < 64; j++) a += b0[j] * W1[j * 64 + t];
    sb01[t] = a;
  }
  __syncthreads();
  for (int idx = t; idx < 4096; idx += 256) {
    int G = idx >> 6, f = idx & 63;
    float v = cnt[G] * b1[f] + S[G] * sb01[f];
    v += U[G * 4 + 0] * sW01[0 * 64 + f];
    v += U[G * 4 + 1] * sW01[1 * 64 + f];
    v += U[G * 4 + 2] * sW01[2 * 64 + f];
    v += U[G * 4 + 3] * sW01[3 * 64 + f];
    sA[idx] = v;
  }
  __syncthreads();
  if (t < 64) {
    float mu = 0.f;
    for (int G = 0; G < 64; G++) mu += sA[G * 64 + t];
    mu *= (1.0f / 64.0f);
    float var = 0.f;
    for (int G = 0; G < 64; G++) {
      float d = sA[G * 64 + t] - mu;
      var += d * d;
    }
    var *= (1.0f / 64.0f);
    float s = bn1g[t] / sqrtf(var + EPSF);
    sSc[t] = s;
    sSh[t] = bn1b[t] - mu * s;
  }
  __syncthreads();
  for (int idx = t; idx < 4096; idx += 256) {
    int f = idx & 63;
    sA[idx] = sA[idx] * sSc[f] + sSh[f];
  }
  __syncthreads();
  for (int idx = t; idx < 4096; idx += 256) {
    int G = idx >> 6, f = idx & 63;
    float v = l0b[f];
    for (int j = 0; j < 64; j++) v += sA[G * 64 + j] * l0W[j * 64 + f];
    sB[idx] = v;
  }
  __syncthreads();
  for (int idx = t; idx < 4096; idx += 256) {
    int G = idx >> 6, f = idx & 63;
    float v = l1b[f];
    for (int j = 0; j < 64; j++) v += sB[G * 64 + j] * l1W[j * 64 + f];
    sA[idx] = v;
  }
  __syncthreads();
  if (t < 64) {
    float v = ob[0];
    for (int j = 0; j < 64; j++) v += sA[t * 64 + j] * oW[j];
    out[t] = v;
  }
}

extern "C" void kernel_launch(void* const* d_in, const int* in_sizes, int n_in,
                              void* d_out, int out_size, void* d_ws,
                              size_t ws_size, hipStream_t stream) {
  const float* x = (const float*)d_in[0];
  const int* ei = (const int*)d_in[1];
  const int* batch = (const int*)d_in[2];
  const float* bn0g = (const float*)d_in[3];
  const float* bn0b = (const float*)d_in[4];
  const float* W0 = (const float*)d_in[5];
  const float* b0 = (const float*)d_in[6];
  const float* W1 = (const float*)d_in[7];
  const float* b1 = (const float*)d_in[8];
  const float* bn1g = (const float*)d_in[9];
  const float* bn1b = (const float*)d_in[10];
  const float* l0W = (const float*)d_in[11];
  const float* l0b = (const float*)d_in[12];
  const float* l1W = (const float*)d_in[13];
  const float* l1b = (const float*)d_in[14];
  const float* oW = (const float*)d_in[15];
  const float* ob = (const float*)d_in[16];

  const int N = in_sizes[0] / 4;
  const int E = in_sizes[1] / 2;
  const int R = (N + HB - 1) / HB;           // deg-hist ranges
  const int chunkH = (E + CHK - 1) / CHK;    // deg-hist chunk
  const int RA = (N + HBA - 1) / HBA;        // acc ranges
  const int chunkA = (E + CHKA - 1) / CHKA;  // acc chunk

  size_t off = 0;
  auto alloc = [&](size_t nbytes) {
    size_t cur = (off + 31) & ~(size_t)31;
    off = cur + nbytes;
    return (void*)((char*)d_ws + cur);
  };
  // --- zeroed region first ---
  float* stats = (float*)alloc(8 * 4);
  float* U = (float*)alloc(NGRAPH * 4 * 4);
  float* S = (float*)alloc(NGRAPH * 4);
  float* cnt = (float*)alloc(NGRAPH * 4);
  unsigned* degcnt = (unsigned*)alloc((size_t)N * 4);
  const size_t zero_bytes = off;
  // --- partials (shared by k_hist as u32 and k_accA as float4) ---
  size_t part_bytes_hist = (size_t)CHK * R * HB * 4;
  size_t part_bytes_acc = (size_t)CHKA * RA * HBA * 16;
  size_t part_bytes = part_bytes_hist > part_bytes_acc ? part_bytes_hist
                                                       : part_bytes_acc;
  void* part = alloc(part_bytes);
  float4* xz = (float4*)alloc((size_t)N * 16);
  float4* nodeS = (float4*)alloc((size_t)N * 32);
  const bool fits = (off <= ws_size);

  hipMemsetAsync(d_ws, 0, zero_bytes, stream);
  if (!fits) {
    // fallback acc region aliases the front of part (must be zeroed)
    hipMemsetAsync(part, 0, (size_t)N * 16, stream);
  }

  const float Ninv = 1.0f / (float)N;
  k_bnstats<<<256, 256, 0, stream>>>((const float4*)x, N, stats);
  if (fits) {
    k_hist<<<CHK * R, 256, 0, stream>>>(ei, E, R, chunkH, (unsigned*)part);
    k_degreduce<<<(N + 255) / 256, 256, 0, stream>>>((unsigned*)part, N, R,
                                                     degcnt);
  } else {
    k_degatomic<<<1024, 256, 0, stream>>>(ei, E, degcnt);
  }
  k_prep<<<(N + 255) / 256, 256, 0, stream>>>((const float4*)x, degcnt, N,
                                              stats, bn0g, bn0b, Ninv, xz);
  if (fits) {
    k_accA<<<RA * CHKA, 512, 0, stream>>>(ei, E, RA, chunkA, xz,
                                          (float4*)part);
  } else {
    k_edgeA_f32<<<2048, 256, 0, stream>>>(ei, E, xz, (float4*)part);
  }
  k_nodeB<<<128, 256, 0, stream>>>((const float4*)part, (const float4*)part,
                                   fits ? 1 : 0, degcnt, xz, batch, N, RA,
                                   nodeS, U, S, cnt);
  k_edgeB<<<1024, 256, 0, stream>>>(ei, E, nodeS, U, S);
  k_final<<<1, 256, 0, stream>>>(U, S, cnt, W0, b0, W1, b1, bn1g, bn1b, l0W,
                                 l0b, l1W, l1b, oW, ob, (float*)d_out);
}

// Round 4
// 580.549 us; speedup vs baseline: 1.8065x; 1.8065x over previous
//
#include <hip/hip_runtime.h>
#include <hip/hip_bf16.h>

#define EPSF 1e-5f

static constexpr int NGRAPH = 64;
static constexpr int HBA = 512;   // nodes per dst-range (one block owns one range)
static constexpr int SH = 9;      // log2(HBA)
static constexpr int GB = 256;    // blocks for count/scatter passes
static constexpr int C2 = 5;      // chunks per range in k_edgeC

__device__ __forceinline__ void gAtomicAdd(float* p, float v) {
  unsafeAtomicAdd(p, v);  // native global_atomic_add_f32 on gfx950
}

// ---------- BN0 stats over x [N,4]: sum[4], sumsq[4] -> stats[8] ----------
__global__ void k_bnstats(const float4* __restrict__ x, int N,
                          float* __restrict__ stats) {
  float s[4] = {0, 0, 0, 0}, q[4] = {0, 0, 0, 0};
  for (int i = blockIdx.x * blockDim.x + threadIdx.x; i < N;
       i += gridDim.x * blockDim.x) {
    float4 v = x[i];
    s[0] += v.x; q[0] += v.x * v.x;
    s[1] += v.y; q[1] += v.y * v.y;
    s[2] += v.z; q[2] += v.z * v.z;
    s[3] += v.w; q[3] += v.w * v.w;
  }
#pragma unroll
  for (int o = 32; o > 0; o >>= 1) {
#pragma unroll
    for (int k = 0; k < 4; k++) {
      s[k] += __shfl_down(s[k], o);
      q[k] += __shfl_down(q[k], o);
    }
  }
  if ((threadIdx.x & 63) == 0) {
#pragma unroll
    for (int k = 0; k < 4; k++) {
      gAtomicAdd(&stats[k], s[k]);
      gAtomicAdd(&stats[4 + k], q[k]);
    }
  }
}

// ---------- bucket count: per (bucket, block) histogram --------------------
__global__ void k_bcount(const int* __restrict__ ei, int E, int chunk,
                         unsigned* __restrict__ counts) {
  __shared__ unsigned cnt[256];
  if (threadIdx.x < 256) cnt[threadIdx.x] = 0;
  __syncthreads();
  int g = blockIdx.x;
  int lo = g * chunk, hi = min(E, lo + chunk);
  for (int e = lo + threadIdx.x; e < hi; e += blockDim.x)
    atomicAdd(&cnt[ei[E + e] >> SH], 1u);
  __syncthreads();
  if (threadIdx.x < 256) counts[(size_t)threadIdx.x * GB + g] = cnt[threadIdx.x];
}

// ---------- bucket offsets: exclusive prefix (bucket-major) ----------------
__global__ void k_boffsets(const unsigned* __restrict__ counts, int RA, int E,
                           unsigned* __restrict__ bases,
                           unsigned* __restrict__ bucketStart) {
  __shared__ unsigned total[256];
  __shared__ unsigned start[257];
  int b = threadIdx.x;
  if (b < RA) {
    unsigned run = 0;
    for (int g = 0; g < GB; g++) {
      bases[(size_t)b * GB + g] = run;
      run += counts[(size_t)b * GB + g];
    }
    total[b] = run;
  }
  __syncthreads();
  if (b == 0) {
    unsigned s = 0;
    for (int i = 0; i < RA; i++) {
      start[i] = s;
      s += total[i];
    }
    start[RA] = (unsigned)E;
    for (int i = 0; i <= RA; i++) bucketStart[i] = start[i];
  }
  __syncthreads();
  if (b < RA) {
    unsigned s0 = start[b];
    for (int g = 0; g < GB; g++) bases[(size_t)b * GB + g] += s0;
  }
}

// ---------- bucket scatter: bedges[pos] = (src<<9)|rel ---------------------
__global__ void k_bscatter(const int* __restrict__ ei, int E, int chunk,
                           const unsigned* __restrict__ bases,
                           unsigned* __restrict__ bedges) {
  __shared__ unsigned cursor[256];
  int g = blockIdx.x;
  if (threadIdx.x < 256)
    cursor[threadIdx.x] = bases[(size_t)threadIdx.x * GB + g];
  __syncthreads();
  int lo = g * chunk, hi = min(E, lo + chunk);
  for (int e = lo + threadIdx.x; e < hi; e += blockDim.x) {
    int s = ei[e];
    int d = ei[E + e];
    int b = d >> SH;
    unsigned pos = atomicAdd(&cursor[b], 1u);
    bedges[pos] = ((unsigned)s << SH) | (unsigned)(d & (HBA - 1));
  }
}

__device__ __forceinline__ void bn0_coefs(const float* __restrict__ stats,
                                          const float* __restrict__ g,
                                          const float* __restrict__ b,
                                          float Ninv, float* sc, float* sh) {
#pragma unroll
  for (int k = 0; k < 4; k++) {
    float mu = stats[k] * Ninv;
    float var = stats[4 + k] * Ninv - mu * mu;
    var = var < 0.f ? 0.f : var;
    float s = g[k] / sqrtf(var + EPSF);
    sc[k] = s;
    sh[k] = b[k] - mu * s;
  }
}

// ---------- per-range: degree hist over own bucket -> dinv, xz -------------
__global__ void k_dprep(const unsigned* __restrict__ bedges,
                        const unsigned* __restrict__ bucketStart,
                        const float4* __restrict__ x, int N,
                        const float* __restrict__ stats,
                        const float* __restrict__ bn0g,
                        const float* __restrict__ bn0b, float Ninv,
                        float* __restrict__ dinv, float4* __restrict__ xz) {
  __shared__ unsigned h[HBA];
  int t = threadIdx.x;
  if (t < HBA) h[t] = 0;
  __syncthreads();
  int r = blockIdx.x;
  int lo = bucketStart[r], hi = bucketStart[r + 1];
  for (int e = lo + t; e < hi; e += blockDim.x)
    atomicAdd(&h[bedges[e] & (HBA - 1)], 1u);
  __syncthreads();
  if (t < HBA) {
    int v = (r << SH) + t;
    if (v < N) {
      float sc[4], sh[4];
      bn0_coefs(stats, bn0g, bn0b, Ninv, sc, sh);
      float dv = rsqrtf((float)h[t] + 1.0f);
      dinv[v] = dv;
      float4 xv = x[v];
      float4 z;
      z.x = dv * (xv.x * sc[0] + sh[0]);
      z.y = dv * (xv.y * sc[1] + sh[1]);
      z.z = dv * (xv.z * sc[2] + sh[2]);
      z.w = dv * (xv.w * sc[3] + sh[3]);
      xz[v] = z;
    }
  }
}

// ---------- per-range: accumulate own bucket -> p2, dd, node terms ---------
__global__ void k_accB(const unsigned* __restrict__ bedges,
                       const unsigned* __restrict__ bucketStart,
                       const float4* __restrict__ xz,
                       const float* __restrict__ dinv,
                       const int* __restrict__ batch, int N,
                       float4* __restrict__ p2, float2* __restrict__ dd,
                       float* __restrict__ U, float* __restrict__ S,
                       float* __restrict__ cnt) {
  __shared__ float ax[HBA], ay[HBA], az[HBA], aw[HBA], asd[HBA];
  __shared__ float lac[NGRAPH * 7];
  int t = threadIdx.x;
  if (t < HBA) { ax[t] = 0.f; ay[t] = 0.f; az[t] = 0.f; aw[t] = 0.f; asd[t] = 0.f; }
  if (t < NGRAPH * 7) lac[t] = 0.f;
  __syncthreads();
  int r = blockIdx.x;
  int lo = bucketStart[r], hi = bucketStart[r + 1];
  for (int e = lo + t; e < hi; e += blockDim.x) {
    unsigned p = bedges[e];
    int rel = p & (HBA - 1);
    int s = p >> SH;
    float4 z = xz[s];
    float dvs = dinv[s];
    atomicAdd(&ax[rel], z.x);
    atomicAdd(&ay[rel], z.y);
    atomicAdd(&az[rel], z.z);
    atomicAdd(&aw[rel], z.w);
    atomicAdd(&asd[rel], dvs);
  }
  __syncthreads();
  if (t < HBA) {
    int v = (r << SH) + t;
    if (v < N) {
      float dv = dinv[v];
      float idg = dv * dv;
      float4 z = xz[v];
      float4 pv;
      pv.x = idg * (ax[t] + z.x);
      pv.y = idg * (ay[t] + z.y);
      pv.z = idg * (az[t] + z.z);
      pv.w = idg * (aw[t] + z.w);
      p2[v] = pv;
      int g = batch[v];
      float2 d2; d2.x = dv; d2.y = (float)g;
      dd[v] = d2;
      int g7 = g * 7;
      atomicAdd(&lac[g7 + 0], dv * pv.x);
      atomicAdd(&lac[g7 + 1], dv * pv.y);
      atomicAdd(&lac[g7 + 2], dv * pv.z);
      atomicAdd(&lac[g7 + 3], dv * pv.w);
      atomicAdd(&lac[g7 + 4], idg + dv * asd[t]);  // sigma: self + edge part
      atomicAdd(&lac[g7 + 5], 1.0f);
    }
  }
  __syncthreads();
  if (t < NGRAPH) {
    gAtomicAdd(&U[t * 4 + 0], lac[t * 7 + 0]);
    gAtomicAdd(&U[t * 4 + 1], lac[t * 7 + 1]);
    gAtomicAdd(&U[t * 4 + 2], lac[t * 7 + 2]);
    gAtomicAdd(&U[t * 4 + 3], lac[t * 7 + 3]);
    gAtomicAdd(&S[t], lac[t * 7 + 4]);
    gAtomicAdd(&cnt[t], lac[t * 7 + 5]);
  }
}

// ---------- edge hop-2: U[g(d)] += dinv_d * p2[s], dst side from LDS -------
__global__ void k_edgeC(const unsigned* __restrict__ bedges,
                        const unsigned* __restrict__ bucketStart,
                        const float4* __restrict__ p2,
                        const float2* __restrict__ dd, int N,
                        float* __restrict__ U) {
  __shared__ float2 sdd[HBA];
  __shared__ float lac[8 * NGRAPH * 4];  // per-wave replicas (512 thr = 8 waves)
  int t = threadIdx.x;
  int r = blockIdx.x / C2, c = blockIdx.x % C2;
  if (t < HBA) {
    int v = (r << SH) + t;
    float2 d2;
    if (v < N) d2 = dd[v]; else { d2.x = 0.f; d2.y = 0.f; }
    sdd[t] = d2;
  }
  for (int i = t; i < 8 * NGRAPH * 4; i += blockDim.x) lac[i] = 0.f;
  __syncthreads();
  int blo = bucketStart[r], bhi = bucketStart[r + 1];
  int len = bhi - blo;
  int clen = (len + C2 - 1) / C2;
  int lo = blo + c * clen, hi = min(bhi, lo + clen);
  float* wl = lac + (t >> 6) * (NGRAPH * 4);
  for (int e = lo + t; e < hi; e += blockDim.x) {
    unsigned p = bedges[e];
    int rel = p & (HBA - 1);
    int s = p >> SH;
    float4 pv = p2[s];
    float2 q = sdd[rel];
    int g4 = (int)q.y * 4;
    float w = q.x;
    atomicAdd(&wl[g4 + 0], w * pv.x);
    atomicAdd(&wl[g4 + 1], w * pv.y);
    atomicAdd(&wl[g4 + 2], w * pv.z);
    atomicAdd(&wl[g4 + 3], w * pv.w);
  }
  __syncthreads();
  if (t < NGRAPH * 4) {
    float s = 0.f;
#pragma unroll
    for (int w = 0; w < 8; w++) s += lac[w * (NGRAPH * 4) + t];
    gAtomicAdd(&U[t], s);
  }
}

// ---------- epilogue: g_raw = U@(W0W1)+S*(b0W1)+cnt*b1 -> BN -> MLP --------
__global__ void k_final(const float* __restrict__ U, const float* __restrict__ S,
                        const float* __restrict__ cnt,
                        const float* __restrict__ W0, const float* __restrict__ b0,
                        const float* __restrict__ W1, const float* __restrict__ b1,
                        const float* __restrict__ bn1g,
                        const float* __restrict__ bn1b,
                        const float* __restrict__ l0W, const float* __restrict__ l0b,
                        const float* __restrict__ l1W, const float* __restrict__ l1b,
                        const float* __restrict__ oW, const float* __restrict__ ob,
                        float* __restrict__ out) {
  __shared__ float sW01[4 * 64];
  __shared__ float sb01[64];
  __shared__ float sA[64 * 64];
  __shared__ float sB[64 * 64];
  __shared__ float sSc[64], sSh[64];
  int t = threadIdx.x;
  {
    int k = t >> 6, f = t & 63;
    float a = 0.f;
    for (int j = 0; j < 64; j++) a += W0[k * 64 + j] * W1[j * 64 + f];
    sW01[k * 64 + f] = a;
  }
  if (t < 64) {
    float a = 0.f;
    for (int j = 0; j < 64; j++) a += b0[j] * W1[j * 64 + t];
    sb01[t] = a;
  }
  __syncthreads();
  for (int idx = t; idx < 4096; idx += 256) {
    int G = idx >> 6, f = idx & 63;
    float v = cnt[G] * b1[f] + S[G] * sb01[f];
    v += U[G * 4 + 0] * sW01[0 * 64 + f];
    v += U[G * 4 + 1] * sW01[1 * 64 + f];
    v += U[G * 4 + 2] * sW01[2 * 64 + f];
    v += U[G * 4 + 3] * sW01[3 * 64 + f];
    sA[idx] = v;
  }
  __syncthreads();
  if (t < 64) {
    float mu = 0.f;
    for (int G = 0; G < 64; G++) mu += sA[G * 64 + t];
    mu *= (1.0f / 64.0f);
    float var = 0.f;
    for (int G = 0; G < 64; G++) {
      float d = sA[G * 64 + t] - mu;
      var += d * d;
    }
    var *= (1.0f / 64.0f);
    float s = bn1g[t] / sqrtf(var + EPSF);
    sSc[t] = s;
    sSh[t] = bn1b[t] - mu * s;
  }
  __syncthreads();
  for (int idx = t; idx < 4096; idx += 256) {
    int f = idx & 63;
    sA[idx] = sA[idx] * sSc[f] + sSh[f];
  }
  __syncthreads();
  for (int idx = t; idx < 4096; idx += 256) {
    int G = idx >> 6, f = idx & 63;
    float v = l0b[f];
    for (int j = 0; j < 64; j++) v += sA[G * 64 + j] * l0W[j * 64 + f];
    sB[idx] = v;
  }
  __syncthreads();
  for (int idx = t; idx < 4096; idx += 256) {
    int G = idx >> 6, f = idx & 63;
    float v = l1b[f];
    for (int j = 0; j < 64; j++) v += sB[G * 64 + j] * l1W[j * 64 + f];
    sA[idx] = v;
  }
  __syncthreads();
  if (t < 64) {
    float v = ob[0];
    for (int j = 0; j < 64; j++) v += sA[t * 64 + j] * oW[j];
    out[t] = v;
  }
}

extern "C" void kernel_launch(void* const* d_in, const int* in_sizes, int n_in,
                              void* d_out, int out_size, void* d_ws,
                              size_t ws_size, hipStream_t stream) {
  const float* x = (const float*)d_in[0];
  const int* ei = (const int*)d_in[1];
  const int* batch = (const int*)d_in[2];
  const float* bn0g = (const float*)d_in[3];
  const float* bn0b = (const float*)d_in[4];
  const float* W0 = (const float*)d_in[5];
  const float* b0 = (const float*)d_in[6];
  const float* W1 = (const float*)d_in[7];
  const float* b1 = (const float*)d_in[8];
  const float* bn1g = (const float*)d_in[9];
  const float* bn1b = (const float*)d_in[10];
  const float* l0W = (const float*)d_in[11];
  const float* l0b = (const float*)d_in[12];
  const float* l1W = (const float*)d_in[13];
  const float* l1b = (const float*)d_in[14];
  const float* oW = (const float*)d_in[15];
  const float* ob = (const float*)d_in[16];

  const int N = in_sizes[0] / 4;
  const int E = in_sizes[1] / 2;
  const int RA = (N + HBA - 1) >> SH;  // 196 for N=100000 (<=256 required)
  const int chunk = (E + GB - 1) / GB;

  size_t off = 0;
  auto alloc = [&](size_t nbytes) {
    size_t cur = (off + 31) & ~(size_t)31;
    off = cur + nbytes;
    return (void*)((char*)d_ws + cur);
  };
  // --- zeroed region first ---
  float* stats = (float*)alloc(8 * 4);
  float* U = (float*)alloc(NGRAPH * 4 * 4);
  float* S = (float*)alloc(NGRAPH * 4);
  float* cnt = (float*)alloc(NGRAPH * 4);
  const size_t zero_bytes = off;
  // --- rest ---
  unsigned* counts = (unsigned*)alloc((size_t)256 * GB * 4);
  unsigned* bases = (unsigned*)alloc((size_t)256 * GB * 4);
  unsigned* bucketStart = (unsigned*)alloc((size_t)(RA + 1) * 4);
  unsigned* bedges = (unsigned*)alloc((size_t)E * 4);
  float* dinv = (float*)alloc((size_t)N * 4);
  float4* xz = (float4*)alloc((size_t)N * 16);
  float4* p2 = (float4*)alloc((size_t)N * 16);
  float2* dd = (float2*)alloc((size_t)N * 8);
  (void)ws_size;

  hipMemsetAsync(d_ws, 0, zero_bytes, stream);

  const float Ninv = 1.0f / (float)N;
  k_bnstats<<<256, 256, 0, stream>>>((const float4*)x, N, stats);
  k_bcount<<<GB, 256, 0, stream>>>(ei, E, chunk, counts);
  k_boffsets<<<1, 256, 0, stream>>>(counts, RA, E, bases, bucketStart);
  k_bscatter<<<GB, 256, 0, stream>>>(ei, E, chunk, bases, bedges);
  k_dprep<<<RA, 1024, 0, stream>>>(bedges, bucketStart, (const float4*)x, N,
                                   stats, bn0g, bn0b, Ninv, dinv, xz);
  k_accB<<<RA, 1024, 0, stream>>>(bedges, bucketStart, xz, dinv, batch, N, p2,
                                  dd, U, S, cnt);
  k_edgeC<<<RA * C2, 512, 0, stream>>>(bedges, bucketStart, p2, dd, N, U);
  k_final<<<1, 256, 0, stream>>>(U, S, cnt, W0, b0, W1, b1, bn1g, bn1b, l0W,
                                 l0b, l1W, l1b, oW, ob, (float*)d_out);
}